// Round 14
// baseline (245.432 us; speedup 1.0000x reference)
//
#include <hip/hip_runtime.h>
#include <math.h>

#define Bz 4
#define Lz 1500
#define Dz 512
#define NHz 8
#define Nz (Bz*Lz)       // 6000 rows
#define PEPSf 1.1920929e-07f

typedef __bf16 bf16x8 __attribute__((ext_vector_type(8)));
typedef unsigned short u16x8 __attribute__((ext_vector_type(8)));
typedef float f32x4 __attribute__((ext_vector_type(4)));
typedef unsigned short us;

__device__ __forceinline__ us f2bf(float f) {
  unsigned u = __float_as_uint(f);
  return (us)((u + 0x7fffu + ((u >> 16) & 1u)) >> 16);
}
__device__ __forceinline__ float bf2f(us b) {
  return __uint_as_float(((unsigned)b) << 16);
}
// tiled bf16 plane: P[((row/16)*64 + col/8)*128 + (row%16)*8 + col%8]
__device__ __forceinline__ int ti_idx(int row, int col) {
  return (((row >> 4) * 64 + (col >> 3)) << 7) + ((row & 15) << 3) + (col & 7);
}
__device__ __forceinline__ void st_tiled(us* __restrict__ P, int row, int col, us v) {
  P[ti_idx(row, col)] = v;
}

// XCD-swizzled block decode (94 row groups of 64 rows; ncg col groups)
__device__ __forceinline__ bool decode_blk(int bx, int ncg, int& R, int& cg) {
  int xcd = bx & 7, v = bx >> 3;
  cg = v % ncg;
  R = (v / ncg) * 8 + xcd;
  return R < 94;
}

// ---------------- merged prep: weights->planes + wqe (blocks 0..223), rowprep (rest) -------
__global__ __launch_bounds__(256) void k_prep(
    const float* __restrict__ W1, const float* __restrict__ W2,
    const float* __restrict__ Wpv, const float* __restrict__ Wpo,
    const float* __restrict__ Wq, const float* __restrict__ Wk,
    const float* __restrict__ Wpk, const float* __restrict__ lq,
    const float* __restrict__ hidden, const float* __restrict__ g, const float* __restrict__ bb,
    us* __restrict__ W1h, us* __restrict__ W2h, us* __restrict__ Wpvh, us* __restrict__ Wpoh,
    us* __restrict__ W1l, us* __restrict__ W2l,
    us* __restrict__ WkTh, us* __restrict__ WkTl, us* __restrict__ WqTh, us* __restrict__ WqTl,
    float* __restrict__ wqe,
    us* __restrict__ Uh, us* __restrict__ Ul, us* __restrict__ HNh) {
  const int t = threadIdx.x;
  const int bx = blockIdx.x;
  if (bx < 224) {
    const int rt = bx & 31, mat = bx >> 5;
    if (mat == 6) {  // wq_eff[h,d] = sum_e lq[h*64+e] * Wpk[h*64+e, d]
      if (rt < 8) {
        for (int d = t; d < Dz; d += 256) {
          float acc = 0.f;
          for (int e = 0; e < 64; ++e) acc += lq[rt * 64 + e] * Wpk[(size_t)(rt * 64 + e) * Dz + d];
          wqe[rt * Dz + d] = acc;
        }
      }
      return;
    }
    const float* S; us* H; us* L = nullptr; bool tr = false;
    switch (mat) {
      case 0: S = W1;  H = W1h;  L = W1l; break;
      case 1: S = W2;  H = W2h;  L = W2l; break;
      case 2: S = Wpv; H = Wpvh; break;
      case 3: S = Wpo; H = Wpoh; break;
      case 4: S = Wk;  H = WkTh; L = WkTl; tr = true; break;
      default: S = Wq; H = WqTh; L = WqTl; tr = true; break;
    }
    for (int e = t; e < 8192; e += 256) {
      int mm = e >> 9, c = e & 511;
      float x = tr ? S[(size_t)c * 512 + (rt * 16 + mm)]
                   : S[(size_t)(rt * 16 + mm) * 512 + c];
      us hb = f2bf(x);
      int off = ((rt * 64 + (c >> 3)) << 7) + (mm << 3) + (c & 7);
      H[off] = hb;
      if (L) L[off] = f2bf(x - bf2f(hb));
    }
    return;
  }
  // ---- rowprep: Uh/Ul = split(l2norm(h)); HNh = bf16(layernorm) ----
  const int row = bx - 224;
  const float* x = hidden + (size_t)row * Dz;
  float x0 = x[t], x1 = x[t + 256];
  float s = x0 + x1, q = x0 * x0 + x1 * x1;
  #pragma unroll
  for (int o = 32; o > 0; o >>= 1) { s += __shfl_xor(s, o, 64); q += __shfl_xor(q, o, 64); }
  __shared__ float ls[4], lqs[4];
  if ((t & 63) == 0) { ls[t >> 6] = s; lqs[t >> 6] = q; }
  __syncthreads();
  s = ls[0] + ls[1] + ls[2] + ls[3];
  q = lqs[0] + lqs[1] + lqs[2] + lqs[3];
  float un = 1.f / fmaxf(sqrtf(q), 1e-8f);
  float u0 = x0 * un, u1 = x1 * un;
  us hb0 = f2bf(u0), hb1 = f2bf(u1);
  st_tiled(Uh, row, t, hb0);       st_tiled(Ul, row, t, f2bf(u0 - bf2f(hb0)));
  st_tiled(Uh, row, t + 256, hb1); st_tiled(Ul, row, t + 256, f2bf(u1 - bf2f(hb1)));
  float mu = s * (1.f / 512.f);
  float var = fmaxf(q * (1.f / 512.f) - mu * mu, 0.f);
  float r = rsqrtf(var + 1e-5f);
  float hn0 = (x0 - mu) * r * g[t] + bb[t];
  float hn1 = (x1 - mu) * r * g[t + 256] + bb[t + 256];
  st_tiled(HNh, row, t, f2bf(hn0));
  st_tiled(HNh, row, t + 256, f2bf(hn1));
}

// ---------------- direct-layout MFMA GEMM body: 64x64 block tile, 32x32 wave tile --------
// no LDS, 1-deep register prefetch (R7-proven). 2x2 frags per wave, ncg=8 col groups.
template<int SPLIT>
__device__ __forceinline__ void gemm_body(
    const us* __restrict__ Ah, const us* __restrict__ Al,
    const us* __restrict__ Bh, const us* __restrict__ Bl,
    const float* __restrict__ bias,
    const us* __restrict__ addH, const us* __restrict__ addL, int doGelu,
    float* __restrict__ outF, us* __restrict__ outH, us* __restrict__ outL,
    int R, int cg, int colbase, int Nrows) {
  const int t = threadIdx.x, w = t >> 6, l = t & 63;
  const int m = l & 15, q = l >> 4;
  const int wr = w & 1, wc = w >> 1;      // wave half-row / half-col within 64x64 tile
  const int laneoff = q * 128 + m * 8;
  const int nrtm1 = (Nrows >> 4) - 1;

  const u16x8* pa[2]; const u16x8* pal[2];
  const u16x8* pb[2]; const u16x8* pbl[2];
  #pragma unroll
  for (int i = 0; i < 2; ++i) {
    int rt = min(R * 4 + wr * 2 + i, nrtm1);   // tail clamp; stores guarded
    pa[i] = (const u16x8*)(Ah + (size_t)rt * 8192 + laneoff);
    if (SPLIT == 3) pal[i] = (const u16x8*)(Al + (size_t)rt * 8192 + laneoff);
  }
  #pragma unroll
  for (int j = 0; j < 2; ++j) {
    int ct = cg * 4 + wc * 2 + j;
    pb[j] = (const u16x8*)(Bh + (size_t)ct * 8192 + laneoff);
    if (SPLIT == 3) pbl[j] = (const u16x8*)(Bl + (size_t)ct * 8192 + laneoff);
  }

  u16x8 bAh[2][2], bAl[2][2], bBh[2][2], bBl[2][2];
  #pragma unroll
  for (int i = 0; i < 2; ++i) {
    bAh[0][i] = pa[i][0];
    if (SPLIT == 3) bAl[0][i] = pal[i][0];
  }
  #pragma unroll
  for (int j = 0; j < 2; ++j) {
    bBh[0][j] = pb[j][0];
    if (SPLIT == 3) bBl[0][j] = pbl[j][0];
  }

  f32x4 acc[2][2];
  #pragma unroll
  for (int i = 0; i < 2; ++i)
    #pragma unroll
    for (int j = 0; j < 2; ++j) acc[i][j] = (f32x4){0.f, 0.f, 0.f, 0.f};

  #pragma unroll 2
  for (int s = 0; s < 16; ++s) {
    const int cur = s & 1, nxt = cur ^ 1;
    const int sn = (s + 1) & 15;      // wrap: final iter reloads step 0 (discarded)
    #pragma unroll
    for (int i = 0; i < 2; ++i) {
      bAh[nxt][i] = pa[i][sn * 64];
      if (SPLIT == 3) bAl[nxt][i] = pal[i][sn * 64];
    }
    #pragma unroll
    for (int j = 0; j < 2; ++j) {
      bBh[nxt][j] = pb[j][sn * 64];
      if (SPLIT == 3) bBl[nxt][j] = pbl[j][sn * 64];
    }
    #pragma unroll
    for (int i = 0; i < 2; ++i)
      #pragma unroll
      for (int j = 0; j < 2; ++j) {
        bf16x8 a = __builtin_bit_cast(bf16x8, bAh[cur][i]);
        bf16x8 b = __builtin_bit_cast(bf16x8, bBh[cur][j]);
        acc[i][j] = __builtin_amdgcn_mfma_f32_16x16x32_bf16(a, b, acc[i][j], 0, 0, 0);
        if (SPLIT == 3) {
          bf16x8 al_ = __builtin_bit_cast(bf16x8, bAl[cur][i]);
          bf16x8 bl_ = __builtin_bit_cast(bf16x8, bBl[cur][j]);
          acc[i][j] = __builtin_amdgcn_mfma_f32_16x16x32_bf16(a, bl_, acc[i][j], 0, 0, 0);
          acc[i][j] = __builtin_amdgcn_mfma_f32_16x16x32_bf16(al_, b, acc[i][j], 0, 0, 0);
        }
      }
  }

  // epilogue: C/D layout col = m, row = q*4 + r
  const int row0 = R * 64 + wr * 32;
  const int col0 = colbase + wc * 32;
  #pragma unroll
  for (int i = 0; i < 2; ++i) {
    #pragma unroll
    for (int r = 0; r < 4; ++r) {
      const int grow = row0 + i * 16 + q * 4 + r;
      if (grow >= Nrows) continue;
      #pragma unroll
      for (int j = 0; j < 2; ++j) {
        const int gcol = col0 + j * 16 + m;
        float v = acc[i][j][r];
        if (bias)   v += bias[gcol];
        if (addH) {
          int ai = ti_idx(grow, gcol);
          v += bf2f(addH[ai]) + bf2f(addL[ai]);
        }
        if (doGelu) v = 0.5f * v * (1.f + erff(v * 0.70710678118654752f));
        if (outF) outF[(size_t)grow * Dz + gcol] = v;
        if (outH) {
          us hb = f2bf(v);
          st_tiled(outH, grow, gcol, hb);
          if (outL) st_tiled(outL, grow, gcol, f2bf(v - bf2f(hb)));
        }
      }
    }
  }
}

// ---- wrapper kernels ----
// z=0: T1 = gelu(U@W1^T+b1); z=1: VALS = HN@Wpv^T; z=2: Gt = Wk^T@Wq (512x512, 64 blocks)
__global__ __launch_bounds__(256, 4) void g_t1_vals_gt(
    const us* Uh, const us* Ul, const us* W1h, const us* W1l, const float* b1, us* T1h, us* T1l,
    const us* HNh, const us* Wpvh, float* VALS,
    const us* WkTh, const us* WkTl, const us* WqTh, const us* WqTl, us* Gth, us* Gtl) {
  if (blockIdx.z == 2) {
    int bx = blockIdx.x;
    if (bx >= 64) return;
    gemm_body<3>(WkTh, WkTl, WqTh, WqTl, nullptr, nullptr, nullptr, 0,
                 nullptr, Gth, Gtl, bx >> 3, bx & 7, (bx & 7) * 64, 512);
    return;
  }
  int R, cg;
  if (!decode_blk(blockIdx.x, 8, R, cg)) return;
  if (blockIdx.z == 0)
    gemm_body<3>(Uh, Ul, W1h, W1l, b1, nullptr, nullptr, 1,
                 nullptr, T1h, T1l, R, cg, cg * 64, Nz);
  else
    gemm_body<1>(HNh, nullptr, Wpvh, nullptr, nullptr, nullptr, nullptr, 0,
                 VALS, nullptr, nullptr, R, cg, cg * 64, Nz);
}

// M = T1@W2^T + b2 + U  (fp32 + tiled hi/lo planes)
__global__ __launch_bounds__(256, 4) void g_w2(
    const us* T1h, const us* T1l, const us* W2h, const us* W2l, const float* b2,
    const us* Uh, const us* Ul, float* M, us* Mh, us* Ml) {
  int R, cg;
  if (!decode_blk(blockIdx.x, 8, R, cg)) return;
  gemm_body<3>(T1h, T1l, W2h, W2l, b2, Uh, Ul, 0, M, Mh, Ml, R, cg, cg * 64, Nz);
}

// P = M @ Gt^T   (normalization folded into k_probs)
__global__ __launch_bounds__(256, 4) void g_p(
    const us* Mh, const us* Ml, const us* Gth, const us* Gtl, float* P) {
  int R, cg;
  if (!decode_blk(blockIdx.x, 8, R, cg)) return;
  gemm_body<3>(Mh, Ml, Gth, Gtl, nullptr, nullptr, nullptr, 0,
               P, nullptr, nullptr, R, cg, cg * 64, Nz);
}

__global__ __launch_bounds__(256, 4) void g_out(
    const us* Ph, const us* Wpoh, float* out) {
  int R, cg;
  if (!decode_blk(blockIdx.x, 8, R, cg)) return;
  gemm_body<1>(Ph, nullptr, Wpoh, nullptr, nullptr, nullptr, nullptr, 0,
               out, nullptr, nullptr, R, cg, cg * 64, Nz);
}

// ---------------- cos(l) = un_l * un_{l+1} * dot(P_l, M_{l+1}) -> probs ----------------
// 256 threads = 4 waves; wave w handles l = blockIdx.x*4 + w.
__global__ __launch_bounds__(256) void k_probs(const float* __restrict__ P,
    const float* __restrict__ M, const float* __restrict__ simb,
    float* __restrict__ probs) {
  const int w = threadIdx.x >> 6, t = threadIdx.x & 63;
  const int l = blockIdx.x * 4 + w, b = blockIdx.y;
  if (l >= Lz) return;
  if (l == Lz - 1) { if (t == 0) probs[(size_t)b * Lz + l] = 0.f; return; }
  const float* pp = P + ((size_t)b * Lz + l) * Dz;
  const float* m0 = M + ((size_t)b * Lz + l) * Dz;
  const float* m1 = M + ((size_t)b * Lz + l + 1) * Dz;
  float accd = 0.f, q0 = 0.f, q1 = 0.f;
  for (int i = t; i < Dz; i += 64) {
    float a = pp[i], x0 = m0[i], x1 = m1[i];
    accd += a * x1; q0 += x0 * x0; q1 += x1 * x1;
  }
  #pragma unroll
  for (int o = 32; o > 0; o >>= 1) {
    accd += __shfl_xor(accd, o, 64);
    q0 += __shfl_xor(q0, o, 64);
    q1 += __shfl_xor(q1, o, 64);
  }
  if (t == 0) {
    float un0 = 1.f / fmaxf(sqrtf(q0), 1e-8f);
    float un1 = 1.f / fmaxf(sqrtf(q1), 1e-8f);
    float cosv = accd * un0 * un1;
    float p = (1.f - (cosv + simb[0])) * 0.5f;
    probs[(size_t)b * Lz + l] = fminf(fmaxf(p, 0.f), 1.f);
  }
}

// ---------------- boundaries + scan ----------------
__global__ __launch_bounds__(256) void k_boundary(const float* __restrict__ probs,
    const float* __restrict__ un, const float* __restrict__ lengths,
    int* __restrict__ seg_start, int* __restrict__ seg_meta) {
  const int b = blockIdx.x, t = threadIdx.x;
  __shared__ float hard[Lz];
  __shared__ float ps[256];
  __shared__ float ws4[4];
  const float len = lengths[b];
  const int valid_len = min((int)(len * (Lz + 1)) - 1, Lz);
  const int Lm = (int)(len * Lz);
  const bool trunc = valid_len < Lz;
  for (int l = t; l < Lz; l += 256) {
    float p = probs[(size_t)b * Lz + l];
    p = fminf(fmaxf(p, PEPSf), 1.f - PEPSf);
    float u = un[(size_t)b * Lz + l];
    u = fminf(fmaxf(u, PEPSf), 1.f - PEPSf);
    float z = logf(p) - log1pf(-p) + logf(u) - log1pf(-u);
    float soft = 1.f / (1.f + expf(-z));
    float hd = soft > 0.5f ? 1.f : 0.f;
    if (trunc && l >= valid_len) hd = (l == valid_len) ? 1.f : 0.f;
    hard[l] = hd;
  }
  __syncthreads();
  float sm = 0.f;
  for (int l = t; l < Lz; l += 256) sm += hard[l];
  #pragma unroll
  for (int o = 32; o > 0; o >>= 1) sm += __shfl_xor(sm, o, 64);
  if ((t & 63) == 0) ws4[t >> 6] = sm;
  __syncthreads();
  float total = ws4[0] + ws4[1] + ws4[2] + ws4[3];
  if (total == 0.f && t == 0) hard[min(valid_len, Lz - 1)] = 1.f;
  __syncthreads();
  const int l0 = t * 6;
  float loc = 0.f;
  for (int i = 0; i < 6; ++i) { int l = l0 + i; if (l < Lz) loc += hard[l]; }
  ps[t] = loc;
  __syncthreads();
  for (int off = 1; off < 256; off <<= 1) {
    float v = (t >= off) ? ps[t - off] : 0.f;
    __syncthreads();
    ps[t] += v;
    __syncthreads();
  }
  float run = ps[t] - loc;
  for (int i = 0; i < 6; ++i) {
    int l = l0 + i; if (l >= Lz) break;
    int seg = (int)(run + 0.5f);
    if (l == 0) seg_start[b * (Lz + 1) + 0] = 0;
    else if (hard[l - 1] > 0.5f) seg_start[b * (Lz + 1) + seg] = l;
    if (l == Lz - 1) {
      int nseg = seg + 1;
      seg_meta[b * 2 + 0] = nseg;
      seg_meta[b * 2 + 1] = Lm;
      seg_start[b * (Lz + 1) + nseg] = Lz;
    }
    run += hard[l];
  }
}

// ---------------- segment softmax-pool -> POOLED hi plane ----------------
// base computed on the fly: base(l,h) = 0.125 * dot(HN[l], wqe[h])  (bf16 HN plane)
__global__ __launch_bounds__(256) void k_pool(const us* __restrict__ HNh,
    const float* __restrict__ wqe,
    const float* __restrict__ VALS, const int* __restrict__ seg_start,
    const int* __restrict__ seg_meta, us* __restrict__ Ph) {
  const int s = blockIdx.x, b = blockIdx.y, t = threadIdx.x;
  const int orow = b * Lz + s;
  const int nseg = seg_meta[b * 2], Lm = seg_meta[b * 2 + 1];
  int start = 0, end = 0;
  bool empty = true;
  if (s < nseg) {
    start = seg_start[b * (Lz + 1) + s];
    end = min(seg_start[b * (Lz + 1) + s + 1], Lm);
    empty = start >= end;
  }
  if (empty) { st_tiled(Ph, orow, t, 0); st_tiled(Ph, orow, t + 256, 0); return; }
  const int h = t >> 5, lane = t & 31;
  // cache wqe row for this head: 16 floats per lane
  float wq[16];
  #pragma unroll
  for (int o = 0; o < 16; ++o) wq[o] = wqe[h * Dz + o * 32 + lane];
  // pass 1: max over segment rows
  float m = -1e30f;
  for (int l = start; l < end; ++l) {
    const int grow = b * Lz + l;
    float acc = 0.f;
    #pragma unroll
    for (int o = 0; o < 16; ++o) acc += bf2f(HNh[ti_idx(grow, o * 32 + lane)]) * wq[o];
    #pragma unroll
    for (int o2 = 16; o2 > 0; o2 >>= 1) acc += __shfl_xor(acc, o2, 32);
    m = fmaxf(m, acc * 0.125f);
  }
  // pass 2: den + weighted accumulate (den identical on all lanes)
  float den = 0.f, a0 = 0.f, a1 = 0.f;
  const float* vp = VALS + (size_t)b * Lz * Dz + h * 64 + lane;
  for (int l = start; l < end; ++l) {
    const int grow = b * Lz + l;
    float acc = 0.f;
    #pragma unroll
    for (int o = 0; o < 16; ++o) acc += bf2f(HNh[ti_idx(grow, o * 32 + lane)]) * wq[o];
    #pragma unroll
    for (int o2 = 16; o2 > 0; o2 >>= 1) acc += __shfl_xor(acc, o2, 32);
    float wgt = expf(acc * 0.125f - m);
    den += wgt;
    a0 += wgt * vp[(size_t)l * Dz];
    a1 += wgt * vp[(size_t)l * Dz + 32];
  }
  float inv = 1.f / den;
  st_tiled(Ph, orow, h * 64 + lane, f2bf(a0 * inv));
  st_tiled(Ph, orow, h * 64 + lane + 32, f2bf(a1 * inv));
}

extern "C" void kernel_launch(void* const* d_in, const int* in_sizes, int n_in,
                              void* d_out, int out_size, void* d_ws, size_t ws_size,
                              hipStream_t stream) {
  const float* hidden  = (const float*)d_in[0];
  const float* lengths = (const float*)d_in[1];
  const float* unoise  = (const float*)d_in[2];
  const float* W1  = (const float*)d_in[3];
  const float* b1  = (const float*)d_in[4];
  const float* W2  = (const float*)d_in[5];
  const float* b2  = (const float*)d_in[6];
  const float* Wq  = (const float*)d_in[7];
  const float* Wk  = (const float*)d_in[8];
  const float* simb   = (const float*)d_in[9];
  const float* lquery = (const float*)d_in[10];
  const float* Wpk = (const float*)d_in[11];
  const float* Wpv = (const float*)d_in[12];
  const float* Wpo = (const float*)d_in[13];
  const float* lng = (const float*)d_in[14];
  const float* lnb = (const float*)d_in[15];
  float* out = (float*)d_out;

  char* p = (char*)d_ws;
  const size_t SF = (size_t)Nz * Dz * 4;          // 12,288,000 B
  const size_t TP = (size_t)376 * 8192 * 2;       // 6,160,384 B
  const size_t WP = (size_t)32 * 8192 * 2;        // 524,288 B
  float* M    = (float*)p; p += SF;
  float* PF   = (float*)p; p += SF;
  float* VALS = (float*)p; p += SF;
  us* Uh  = (us*)p; p += TP;
  us* Ul  = (us*)p; p += TP;
  us* T1h = (us*)p; p += TP;
  us* T1l = (us*)p; p += TP;
  us* Mh  = (us*)p; p += TP;
  us* Ml  = (us*)p; p += TP;
  us* HNh = (us*)p; p += TP;
  us* Ph  = (us*)p; p += TP;
  us* W1h = (us*)p; p += WP;
  us* W1l = (us*)p; p += WP;
  us* W2h = (us*)p; p += WP;
  us* W2l = (us*)p; p += WP;
  us* Wpvh = (us*)p; p += WP;
  us* Wpoh = (us*)p; p += WP;
  us* WkTh = (us*)p; p += WP;
  us* WkTl = (us*)p; p += WP;
  us* WqTh = (us*)p; p += WP;
  us* WqTl = (us*)p; p += WP;
  us* Gth  = (us*)p; p += WP;
  us* Gtl  = (us*)p; p += WP;
  float* probs  = (float*)p; p += 24064;
  int* segst    = (int*)p;   p += 24064;
  int* segmeta  = (int*)p;   p += 256;
  float* wqe    = (float*)p;

  const int G8 = 8 * 12 * 8;   // 768 swizzle slots (752 used), 64x64 tiles

  k_prep<<<224 + Nz, 256, 0, stream>>>(W1, W2, Wpv, Wpo, Wq, Wk, Wpk, lquery,
      hidden, lng, lnb,
      W1h, W2h, Wpvh, Wpoh, W1l, W2l, WkTh, WkTl, WqTh, WqTl, wqe, Uh, Ul, HNh);
  g_t1_vals_gt<<<dim3(G8, 1, 3), 256, 0, stream>>>(Uh, Ul, W1h, W1l, b1, T1h, T1l,
      HNh, Wpvh, VALS, WkTh, WkTl, WqTh, WqTl, Gth, Gtl);        // T1, VALS, Gt
  g_w2<<<G8, 256, 0, stream>>>(T1h, T1l, W2h, W2l, b2, Uh, Ul, M, Mh, Ml);  // M(+planes)
  g_p<<<G8, 256, 0, stream>>>(Mh, Ml, Gth, Gtl, PF);             // P = M@Gt^T
  k_probs<<<dim3(375, Bz), 256, 0, stream>>>(PF, M, simb, probs);
  k_boundary<<<Bz, 256, 0, stream>>>(probs, unoise, lengths, segst, segmeta);
  k_pool<<<dim3(Lz, Bz), 256, 0, stream>>>(HNh, wqe, VALS, segst, segmeta, Ph);
  g_out<<<G8, 256, 0, stream>>>(Ph, Wpoh, out);                  // out = POOLED@Wpo^T
}

// Round 15
// 231.934 us; speedup vs baseline: 1.0582x; 1.0582x over previous
//
#include <hip/hip_runtime.h>
#include <math.h>

#define Bz 4
#define Lz 1500
#define Dz 512
#define NHz 8
#define Nz (Bz*Lz)       // 6000 rows
#define PEPSf 1.1920929e-07f

typedef __bf16 bf16x8 __attribute__((ext_vector_type(8)));
typedef unsigned short u16x8 __attribute__((ext_vector_type(8)));
typedef float f32x4 __attribute__((ext_vector_type(4)));
typedef unsigned short us;

__device__ __forceinline__ us f2bf(float f) {
  unsigned u = __float_as_uint(f);
  return (us)((u + 0x7fffu + ((u >> 16) & 1u)) >> 16);
}
__device__ __forceinline__ float bf2f(us b) {
  return __uint_as_float(((unsigned)b) << 16);
}
// tiled bf16 plane: P[((row/16)*64 + col/8)*128 + (row%16)*8 + col%8]
__device__ __forceinline__ int ti_idx(int row, int col) {
  return (((row >> 4) * 64 + (col >> 3)) << 7) + ((row & 15) << 3) + (col & 7);
}
__device__ __forceinline__ void st_tiled(us* __restrict__ P, int row, int col, us v) {
  P[ti_idx(row, col)] = v;
}

// XCD-swizzled block decode (94 row groups of 64 rows; ncg col groups)
__device__ __forceinline__ bool decode_blk(int bx, int ncg, int& R, int& cg) {
  int xcd = bx & 7, v = bx >> 3;
  cg = v % ncg;
  R = (v / ncg) * 8 + xcd;
  return R < 94;
}

// ---------------- weights -> tiled planes; also WkT/WqT planes and wq_eff ----------------
__global__ __launch_bounds__(256) void k_wconv(
    const float* __restrict__ s0, const float* __restrict__ s1, const float* __restrict__ s2,
    const float* __restrict__ s3,  // W1, W2, Wpv, Wpo
    const float* __restrict__ Wq, const float* __restrict__ Wk,
    const float* __restrict__ Wpk, const float* __restrict__ lq,
    us* __restrict__ h0, us* __restrict__ h1, us* __restrict__ h2, us* __restrict__ h3,
    us* __restrict__ l0, us* __restrict__ l1,
    us* __restrict__ WkTh, us* __restrict__ WkTl, us* __restrict__ WqTh, us* __restrict__ WqTl,
    float* __restrict__ wqe) {
  const int rt = blockIdx.x, mat = blockIdx.y, t = threadIdx.x;
  if (mat == 8) {  // wq_eff[h,d] = sum_e lq[h*64+e] * Wpk[h*64+e, d]
    if (rt < 8) {
      for (int d = t; d < Dz; d += 256) {
        float acc = 0.f;
        for (int e = 0; e < 64; ++e) acc += lq[rt * 64 + e] * Wpk[(size_t)(rt * 64 + e) * Dz + d];
        wqe[rt * Dz + d] = acc;
      }
    }
    return;
  }
  const float* S; us* H; us* L = nullptr; bool tr = false;
  switch (mat) {
    case 0: S = s0; H = h0; L = l0; break;            // W1 hi/lo
    case 1: S = s1; H = h1; L = l1; break;            // W2 hi/lo
    case 2: S = s2; H = h2; break;                    // Wpv hi
    case 3: S = s3; H = h3; break;                    // Wpo hi
    case 4: S = Wk; H = WkTh; L = WkTl; tr = true; break;  // Wk^T hi/lo
    default: S = Wq; H = WqTh; L = WqTl; tr = true; break; // Wq^T hi/lo
  }
  for (int e = t; e < 8192; e += 256) {
    int mm = e >> 9, c = e & 511;
    float x = tr ? S[(size_t)c * 512 + (rt * 16 + mm)]
                 : S[(size_t)(rt * 16 + mm) * 512 + c];
    us hb = f2bf(x);
    int off = ((rt * 64 + (c >> 3)) << 7) + (mm << 3) + (c & 7);
    H[off] = hb;
    if (L) L[off] = f2bf(x - bf2f(hb));
  }
}

// ---------------- row prep: Uh/Ul = split(l2norm(h)); HNh = bf16(layernorm); base fused ----
__global__ __launch_bounds__(256) void k_rowprep(const float* __restrict__ h,
    const float* __restrict__ g, const float* __restrict__ bb,
    const float* __restrict__ wqe,
    us* __restrict__ Uh, us* __restrict__ Ul, us* __restrict__ HNh,
    float* __restrict__ base) {
  const int row = blockIdx.x;
  const int t = threadIdx.x;
  const float* x = h + (size_t)row * Dz;
  float x0 = x[t], x1 = x[t + 256];
  float s = x0 + x1, q = x0 * x0 + x1 * x1;
  #pragma unroll
  for (int o = 32; o > 0; o >>= 1) { s += __shfl_xor(s, o, 64); q += __shfl_xor(q, o, 64); }
  __shared__ float ls[4], lq[4];
  __shared__ float xs[Dz];
  if ((t & 63) == 0) { ls[t >> 6] = s; lq[t >> 6] = q; }
  __syncthreads();
  s = ls[0] + ls[1] + ls[2] + ls[3];
  q = lq[0] + lq[1] + lq[2] + lq[3];
  float un = 1.f / fmaxf(sqrtf(q), 1e-8f);
  float u0 = x0 * un, u1 = x1 * un;
  us hb0 = f2bf(u0), hb1 = f2bf(u1);
  st_tiled(Uh, row, t, hb0);       st_tiled(Ul, row, t, f2bf(u0 - bf2f(hb0)));
  st_tiled(Uh, row, t + 256, hb1); st_tiled(Ul, row, t + 256, f2bf(u1 - bf2f(hb1)));
  float mu = s * (1.f / 512.f);
  float var = fmaxf(q * (1.f / 512.f) - mu * mu, 0.f);
  float r = rsqrtf(var + 1e-5f);
  float hn0 = (x0 - mu) * r * g[t] + bb[t];
  float hn1 = (x1 - mu) * r * g[t + 256] + bb[t + 256];
  st_tiled(HNh, row, t, f2bf(hn0));
  st_tiled(HNh, row, t + 256, f2bf(hn1));
  // fused base: full 512-dim dot per head (R6-verified)
  xs[t] = hn0; xs[t + 256] = hn1;
  __syncthreads();
  const int hh = t >> 5, lane = t & 31;
  float accb = 0.f;
  for (int d = lane; d < Dz; d += 32) accb += xs[d] * wqe[hh * Dz + d];
  #pragma unroll
  for (int o = 16; o > 0; o >>= 1) accb += __shfl_xor(accb, o, 32);
  if (lane == 0) base[(size_t)row * NHz + hh] = accb * 0.125f;
}

// ---------------- direct-layout MFMA GEMM body: 64x64 block tile, 32x32 wave tile --------
// no LDS, 1-deep register prefetch (R7-proven). 2x2 frags per wave, ncg=8 col groups.
template<int SPLIT>
__device__ __forceinline__ void gemm_body(
    const us* __restrict__ Ah, const us* __restrict__ Al,
    const us* __restrict__ Bh, const us* __restrict__ Bl,
    const float* __restrict__ bias,
    const us* __restrict__ addH, const us* __restrict__ addL, int doGelu,
    float* __restrict__ outF, us* __restrict__ outR,
    us* __restrict__ outH, us* __restrict__ outL,
    int R, int cg, int colbase, int Nrows) {
  const int t = threadIdx.x, w = t >> 6, l = t & 63;
  const int m = l & 15, q = l >> 4;
  const int wr = w & 1, wc = w >> 1;      // wave half-row / half-col within 64x64 tile
  const int laneoff = q * 128 + m * 8;
  const int nrtm1 = (Nrows >> 4) - 1;

  const u16x8* pa[2]; const u16x8* pal[2];
  const u16x8* pb[2]; const u16x8* pbl[2];
  #pragma unroll
  for (int i = 0; i < 2; ++i) {
    int rt = min(R * 4 + wr * 2 + i, nrtm1);   // tail clamp; stores guarded
    pa[i] = (const u16x8*)(Ah + (size_t)rt * 8192 + laneoff);
    if (SPLIT == 3) pal[i] = (const u16x8*)(Al + (size_t)rt * 8192 + laneoff);
  }
  #pragma unroll
  for (int j = 0; j < 2; ++j) {
    int ct = cg * 4 + wc * 2 + j;
    pb[j] = (const u16x8*)(Bh + (size_t)ct * 8192 + laneoff);
    if (SPLIT == 3) pbl[j] = (const u16x8*)(Bl + (size_t)ct * 8192 + laneoff);
  }

  u16x8 bAh[2][2], bAl[2][2], bBh[2][2], bBl[2][2];
  #pragma unroll
  for (int i = 0; i < 2; ++i) {
    bAh[0][i] = pa[i][0];
    if (SPLIT == 3) bAl[0][i] = pal[i][0];
  }
  #pragma unroll
  for (int j = 0; j < 2; ++j) {
    bBh[0][j] = pb[j][0];
    if (SPLIT == 3) bBl[0][j] = pbl[j][0];
  }

  f32x4 acc[2][2];
  #pragma unroll
  for (int i = 0; i < 2; ++i)
    #pragma unroll
    for (int j = 0; j < 2; ++j) acc[i][j] = (f32x4){0.f, 0.f, 0.f, 0.f};

  #pragma unroll 2
  for (int s = 0; s < 16; ++s) {
    const int cur = s & 1, nxt = cur ^ 1;
    const int sn = (s + 1) & 15;      // wrap: final iter reloads step 0 (discarded)
    #pragma unroll
    for (int i = 0; i < 2; ++i) {
      bAh[nxt][i] = pa[i][sn * 64];
      if (SPLIT == 3) bAl[nxt][i] = pal[i][sn * 64];
    }
    #pragma unroll
    for (int j = 0; j < 2; ++j) {
      bBh[nxt][j] = pb[j][sn * 64];
      if (SPLIT == 3) bBl[nxt][j] = pbl[j][sn * 64];
    }
    #pragma unroll
    for (int i = 0; i < 2; ++i)
      #pragma unroll
      for (int j = 0; j < 2; ++j) {
        bf16x8 a = __builtin_bit_cast(bf16x8, bAh[cur][i]);
        bf16x8 b = __builtin_bit_cast(bf16x8, bBh[cur][j]);
        acc[i][j] = __builtin_amdgcn_mfma_f32_16x16x32_bf16(a, b, acc[i][j], 0, 0, 0);
        if (SPLIT == 3) {
          bf16x8 al_ = __builtin_bit_cast(bf16x8, bAl[cur][i]);
          bf16x8 bl_ = __builtin_bit_cast(bf16x8, bBl[cur][j]);
          acc[i][j] = __builtin_amdgcn_mfma_f32_16x16x32_bf16(a, bl_, acc[i][j], 0, 0, 0);
          acc[i][j] = __builtin_amdgcn_mfma_f32_16x16x32_bf16(al_, b, acc[i][j], 0, 0, 0);
        }
      }
  }

  // epilogue: C/D layout col = m, row = q*4 + r
  const int row0 = R * 64 + wr * 32;
  const int col0 = colbase + wc * 32;
  #pragma unroll
  for (int i = 0; i < 2; ++i) {
    #pragma unroll
    for (int r = 0; r < 4; ++r) {
      const int grow = row0 + i * 16 + q * 4 + r;
      if (grow >= Nrows) continue;
      #pragma unroll
      for (int j = 0; j < 2; ++j) {
        const int gcol = col0 + j * 16 + m;
        float v = acc[i][j][r];
        if (bias)   v += bias[gcol];
        if (addH) {
          int ai = ti_idx(grow, gcol);
          v += bf2f(addH[ai]) + bf2f(addL[ai]);
        }
        if (doGelu) v = 0.5f * v * (1.f + erff(v * 0.70710678118654752f));
        if (outF) outF[(size_t)grow * Dz + gcol] = v;
        if (outR) outR[(size_t)grow * Dz + gcol] = f2bf(v);
        if (outH) {
          us hb = f2bf(v);
          st_tiled(outH, grow, gcol, hb);
          if (outL) st_tiled(outL, grow, gcol, f2bf(v - bf2f(hb)));
        }
      }
    }
  }
}

// ---- wrapper kernels ----
// z=0: T1 = gelu(U@W1^T+b1); z=1: VALSb = bf16(HN@Wpv^T); z=2: Gt = Wk^T@Wq (512x512, 64 blocks)
__global__ __launch_bounds__(256, 4) void g_t1_vals_gt(
    const us* Uh, const us* Ul, const us* W1h, const us* W1l, const float* b1, us* T1h, us* T1l,
    const us* HNh, const us* Wpvh, us* VALSb,
    const us* WkTh, const us* WkTl, const us* WqTh, const us* WqTl, us* Gth, us* Gtl) {
  if (blockIdx.z == 2) {
    int bx = blockIdx.x;
    if (bx >= 64) return;
    gemm_body<3>(WkTh, WkTl, WqTh, WqTl, nullptr, nullptr, nullptr, 0,
                 nullptr, nullptr, Gth, Gtl, bx >> 3, bx & 7, (bx & 7) * 64, 512);
    return;
  }
  int R, cg;
  if (!decode_blk(blockIdx.x, 8, R, cg)) return;
  if (blockIdx.z == 0)
    gemm_body<3>(Uh, Ul, W1h, W1l, b1, nullptr, nullptr, 1,
                 nullptr, nullptr, T1h, T1l, R, cg, cg * 64, Nz);
  else
    gemm_body<1>(HNh, nullptr, Wpvh, nullptr, nullptr, nullptr, nullptr, 0,
                 nullptr, VALSb, nullptr, nullptr, R, cg, cg * 64, Nz);
}

// M = T1@W2^T + b2 + U  (fp32 + tiled hi/lo planes)
__global__ __launch_bounds__(256, 4) void g_w2(
    const us* T1h, const us* T1l, const us* W2h, const us* W2l, const float* b2,
    const us* Uh, const us* Ul, float* M, us* Mh, us* Ml) {
  int R, cg;
  if (!decode_blk(blockIdx.x, 8, R, cg)) return;
  gemm_body<3>(T1h, T1l, W2h, W2l, b2, Uh, Ul, 0, M, nullptr, Mh, Ml, R, cg, cg * 64, Nz);
}

// P = M @ Gt^T   (normalization folded into k_probs)
__global__ __launch_bounds__(256, 4) void g_p(
    const us* Mh, const us* Ml, const us* Gth, const us* Gtl, float* P) {
  int R, cg;
  if (!decode_blk(blockIdx.x, 8, R, cg)) return;
  gemm_body<3>(Mh, Ml, Gth, Gtl, nullptr, nullptr, nullptr, 0,
               P, nullptr, nullptr, nullptr, R, cg, cg * 64, Nz);
}

__global__ __launch_bounds__(256, 4) void g_out(
    const us* Ph, const us* Wpoh, float* out) {
  int R, cg;
  if (!decode_blk(blockIdx.x, 8, R, cg)) return;
  gemm_body<1>(Ph, nullptr, Wpoh, nullptr, nullptr, nullptr, nullptr, 0,
               out, nullptr, nullptr, nullptr, R, cg, cg * 64, Nz);
}

// ---------------- cos(l) = un_l * un_{l+1} * dot(P_l, M_{l+1}) -> probs ----------------
// 256 threads = 4 waves; wave w handles l = blockIdx.x*4 + w.
__global__ __launch_bounds__(256) void k_probs(const float* __restrict__ P,
    const float* __restrict__ M, const float* __restrict__ simb,
    float* __restrict__ probs) {
  const int w = threadIdx.x >> 6, t = threadIdx.x & 63;
  const int l = blockIdx.x * 4 + w, b = blockIdx.y;
  if (l >= Lz) return;
  if (l == Lz - 1) { if (t == 0) probs[(size_t)b * Lz + l] = 0.f; return; }
  const float* pp = P + ((size_t)b * Lz + l) * Dz;
  const float* m0 = M + ((size_t)b * Lz + l) * Dz;
  const float* m1 = M + ((size_t)b * Lz + l + 1) * Dz;
  float accd = 0.f, q0 = 0.f, q1 = 0.f;
  for (int i = t; i < Dz; i += 64) {
    float a = pp[i], x0 = m0[i], x1 = m1[i];
    accd += a * x1; q0 += x0 * x0; q1 += x1 * x1;
  }
  #pragma unroll
  for (int o = 32; o > 0; o >>= 1) {
    accd += __shfl_xor(accd, o, 64);
    q0 += __shfl_xor(q0, o, 64);
    q1 += __shfl_xor(q1, o, 64);
  }
  if (t == 0) {
    float un0 = 1.f / fmaxf(sqrtf(q0), 1e-8f);
    float un1 = 1.f / fmaxf(sqrtf(q1), 1e-8f);
    float cosv = accd * un0 * un1;
    float p = (1.f - (cosv + simb[0])) * 0.5f;
    probs[(size_t)b * Lz + l] = fminf(fmaxf(p, 0.f), 1.f);
  }
}

// ---------------- boundaries + scan ----------------
__global__ __launch_bounds__(256) void k_boundary(const float* __restrict__ probs,
    const float* __restrict__ un, const float* __restrict__ lengths,
    int* __restrict__ seg_start, int* __restrict__ seg_meta) {
  const int b = blockIdx.x, t = threadIdx.x;
  __shared__ float hard[Lz];
  __shared__ float ps[256];
  __shared__ float ws4[4];
  const float len = lengths[b];
  const int valid_len = min((int)(len * (Lz + 1)) - 1, Lz);
  const int Lm = (int)(len * Lz);
  const bool trunc = valid_len < Lz;
  for (int l = t; l < Lz; l += 256) {
    float p = probs[(size_t)b * Lz + l];
    p = fminf(fmaxf(p, PEPSf), 1.f - PEPSf);
    float u = un[(size_t)b * Lz + l];
    u = fminf(fmaxf(u, PEPSf), 1.f - PEPSf);
    float z = logf(p) - log1pf(-p) + logf(u) - log1pf(-u);
    float soft = 1.f / (1.f + expf(-z));
    float hd = soft > 0.5f ? 1.f : 0.f;
    if (trunc && l >= valid_len) hd = (l == valid_len) ? 1.f : 0.f;
    hard[l] = hd;
  }
  __syncthreads();
  float sm = 0.f;
  for (int l = t; l < Lz; l += 256) sm += hard[l];
  #pragma unroll
  for (int o = 32; o > 0; o >>= 1) sm += __shfl_xor(sm, o, 64);
  if ((t & 63) == 0) ws4[t >> 6] = sm;
  __syncthreads();
  float total = ws4[0] + ws4[1] + ws4[2] + ws4[3];
  if (total == 0.f && t == 0) hard[min(valid_len, Lz - 1)] = 1.f;
  __syncthreads();
  const int l0 = t * 6;
  float loc = 0.f;
  for (int i = 0; i < 6; ++i) { int l = l0 + i; if (l < Lz) loc += hard[l]; }
  ps[t] = loc;
  __syncthreads();
  for (int off = 1; off < 256; off <<= 1) {
    float v = (t >= off) ? ps[t - off] : 0.f;
    __syncthreads();
    ps[t] += v;
    __syncthreads();
  }
  float run = ps[t] - loc;
  for (int i = 0; i < 6; ++i) {
    int l = l0 + i; if (l >= Lz) break;
    int seg = (int)(run + 0.5f);
    if (l == 0) seg_start[b * (Lz + 1) + 0] = 0;
    else if (hard[l - 1] > 0.5f) seg_start[b * (Lz + 1) + seg] = l;
    if (l == Lz - 1) {
      int nseg = seg + 1;
      seg_meta[b * 2 + 0] = nseg;
      seg_meta[b * 2 + 1] = Lm;
      seg_start[b * (Lz + 1) + nseg] = Lz;
    }
    run += hard[l];
  }
}

// ---------------- segment softmax-pool (VALS bf16 row-major) -> POOLED hi plane ----------
__global__ __launch_bounds__(256) void k_pool(const float* __restrict__ base,
    const us* __restrict__ VALSb, const int* __restrict__ seg_start,
    const int* __restrict__ seg_meta, us* __restrict__ Ph) {
  const int s = blockIdx.x, b = blockIdx.y, t = threadIdx.x;
  const int orow = b * Lz + s;
  const int nseg = seg_meta[b * 2], Lm = seg_meta[b * 2 + 1];
  int start = 0, end = 0;
  bool empty = true;
  if (s < nseg) {
    start = seg_start[b * (Lz + 1) + s];
    end = min(seg_start[b * (Lz + 1) + s + 1], Lm);
    empty = start >= end;
  }
  if (empty) { st_tiled(Ph, orow, t, 0); st_tiled(Ph, orow, t + 256, 0); return; }
  const int h = t >> 5, lane = t & 31;
  const float* bp = base + (size_t)b * Lz * NHz + h;
  float m = -1e30f;
  for (int l = start + lane; l < end; l += 32) m = fmaxf(m, bp[(size_t)l * NHz]);
  #pragma unroll
  for (int o = 16; o > 0; o >>= 1) m = fmaxf(m, __shfl_xor(m, o, 32));
  float den = 0.f;
  for (int l = start + lane; l < end; l += 32) den += expf(bp[(size_t)l * NHz] - m);
  #pragma unroll
  for (int o = 16; o > 0; o >>= 1) den += __shfl_xor(den, o, 32);
  float a0 = 0.f, a1 = 0.f;
  const us* vp = VALSb + (size_t)b * Lz * Dz + h * 64 + lane;
  for (int l = start; l < end; ++l) {
    float wgt = expf(bp[(size_t)l * NHz] - m);
    a0 += wgt * bf2f(vp[(size_t)l * Dz]);
    a1 += wgt * bf2f(vp[(size_t)l * Dz + 32]);
  }
  float inv = 1.f / den;
  st_tiled(Ph, orow, h * 64 + lane, f2bf(a0 * inv));
  st_tiled(Ph, orow, h * 64 + lane + 32, f2bf(a1 * inv));
}

extern "C" void kernel_launch(void* const* d_in, const int* in_sizes, int n_in,
                              void* d_out, int out_size, void* d_ws, size_t ws_size,
                              hipStream_t stream) {
  const float* hidden  = (const float*)d_in[0];
  const float* lengths = (const float*)d_in[1];
  const float* unoise  = (const float*)d_in[2];
  const float* W1  = (const float*)d_in[3];
  const float* b1  = (const float*)d_in[4];
  const float* W2  = (const float*)d_in[5];
  const float* b2  = (const float*)d_in[6];
  const float* Wq  = (const float*)d_in[7];
  const float* Wk  = (const float*)d_in[8];
  const float* simb   = (const float*)d_in[9];
  const float* lquery = (const float*)d_in[10];
  const float* Wpk = (const float*)d_in[11];
  const float* Wpv = (const float*)d_in[12];
  const float* Wpo = (const float*)d_in[13];
  const float* lng = (const float*)d_in[14];
  const float* lnb = (const float*)d_in[15];
  float* out = (float*)d_out;

  char* p = (char*)d_ws;
  const size_t SF = (size_t)Nz * Dz * 4;          // 12,288,000 B
  const size_t TP = (size_t)376 * 8192 * 2;       // 6,160,384 B
  const size_t WP = (size_t)32 * 8192 * 2;        // 524,288 B
  float* M    = (float*)p; p += SF;
  float* PF   = (float*)p; p += SF;
  us* VALSb = (us*)p; p += TP;   // row-major bf16 (Nz*Dz*2 = 6,144,000 <= TP)
  us* Uh  = (us*)p; p += TP;
  us* Ul  = (us*)p; p += TP;
  us* T1h = (us*)p; p += TP;
  us* T1l = (us*)p; p += TP;
  us* Mh  = (us*)p; p += TP;
  us* Ml  = (us*)p; p += TP;
  us* HNh = (us*)p; p += TP;
  us* Ph  = (us*)p; p += TP;
  us* W1h = (us*)p; p += WP;
  us* W1l = (us*)p; p += WP;
  us* W2h = (us*)p; p += WP;
  us* W2l = (us*)p; p += WP;
  us* Wpvh = (us*)p; p += WP;
  us* Wpoh = (us*)p; p += WP;
  us* WkTh = (us*)p; p += WP;
  us* WkTl = (us*)p; p += WP;
  us* WqTh = (us*)p; p += WP;
  us* WqTl = (us*)p; p += WP;
  us* Gth  = (us*)p; p += WP;
  us* Gtl  = (us*)p; p += WP;
  float* probs  = (float*)p; p += 24064;
  float* base   = (float*)p; p += 192000;
  int* segst    = (int*)p;   p += 24064;
  int* segmeta  = (int*)p;   p += 256;
  float* wqe    = (float*)p;

  const int G8 = 8 * 12 * 8;   // 768 swizzle slots (752 used), 64x64 tiles

  k_wconv<<<dim3(32, 9), 256, 0, stream>>>(W1, W2, Wpv, Wpo, Wq, Wk, Wpk, lquery,
      W1h, W2h, Wpvh, Wpoh, W1l, W2l, WkTh, WkTl, WqTh, WqTl, wqe);
  k_rowprep<<<Nz, 256, 0, stream>>>(hidden, lng, lnb, wqe, Uh, Ul, HNh, base);
  g_t1_vals_gt<<<dim3(G8, 1, 3), 256, 0, stream>>>(Uh, Ul, W1h, W1l, b1, T1h, T1l,
      HNh, Wpvh, VALSb, WkTh, WkTl, WqTh, WqTl, Gth, Gtl);       // T1, VALSb, Gt
  g_w2<<<G8, 256, 0, stream>>>(T1h, T1l, W2h, W2l, b2, Uh, Ul, M, Mh, Ml);  // M(+planes)
  g_p<<<G8, 256, 0, stream>>>(Mh, Ml, Gth, Gtl, PF);             // P = M@Gt^T
  k_probs<<<dim3(375, Bz), 256, 0, stream>>>(PF, M, simb, probs);
  k_boundary<<<Bz, 256, 0, stream>>>(probs, unoise, lengths, segst, segmeta);
  k_pool<<<dim3(Lz, Bz), 256, 0, stream>>>(base, VALSb, segst, segmeta, Ph);
  g_out<<<G8, 256, 0, stream>>>(Ph, Wpoh, out);                  // out = POOLED@Wpo^T
}